// Round 12
// baseline (425.158 us; speedup 1.0000x reference)
//
#include <hip/hip_runtime.h>

#define BB 4
#define CC 64
#define HH 128
#define WW 128
#define OO 64
#define HWs (HH*WW)

typedef _Float16 f16;
typedef _Float16 f16x8 __attribute__((ext_vector_type(8)));
typedef _Float16 f16x2 __attribute__((ext_vector_type(2)));
typedef float f32x4 __attribute__((ext_vector_type(4)));

__device__ __forceinline__ size_t xt_idx(int b, int y, int x) {
    return (((size_t)b * HH + y) * WW + x) * CC;
}

// ---------- fused prep: x transpose (NCHW f32 -> NHWC f16) + weight packing ----------
__global__ __launch_bounds__(256) void prep_all(const float* __restrict__ x,
                                                const float* __restrict__ offw,
                                                const float* __restrict__ dw,
                                                f16* __restrict__ xt,
                                                f16* __restrict__ wA_off,
                                                f16* __restrict__ wA_def) {
    const int bid = blockIdx.x;
    const int tid = threadIdx.x;
    if (bid < 512) {
        const int b = bid >> 7, y = bid & 127;
        const int px = tid & 127, half = tid >> 7;
        const float* src = x + (size_t)b * CC * HWs + (size_t)half * 32 * HWs + y * WW + px;
        f16* dst = xt + xt_idx(b, y, px) + half * 32;
        #pragma unroll
        for (int cg = 0; cg < 4; ++cg) {
            f16x8 v;
            #pragma unroll
            for (int j = 0; j < 8; ++j)
                v[j] = (f16)src[(size_t)(cg * 8 + j) * HWs];
            *(f16x8*)(dst + cg * 8) = v;
        }
    } else {
        const int t = (bid - 512) * 256 + tid;
        const int l = t & 63;
        const int idx = t >> 6;
        f16x8 v;
        if (idx < 36) {
            const int mt = idx & 1, ks = idx >> 1;
            const int o = mt * 16 + (l & 15);
            const int tap = ks >> 1, ky = tap / 3, kx = tap % 3;
            #pragma unroll
            for (int i = 0; i < 8; ++i) {
                const int c = (ks & 1) * 32 + (l >> 4) * 8 + i;
                v[i] = (o < 18) ? (f16)offw[((o * CC + c) * 3 + ky) * 3 + kx] : (f16)0.f;
            }
            *(f16x8*)(wA_off + (size_t)(idx * 64 + l) * 8) = v;
        } else if (idx < 108) {
            const int id2 = idx - 36;
            const int mt = id2 & 3, ks = (id2 >> 2) & 1, tap = id2 >> 3;
            const int o = mt * 16 + (l & 15);
            #pragma unroll
            for (int i = 0; i < 8; ++i) {
                const int c = ks * 32 + (l >> 4) * 8 + i;
                v[i] = (f16)dw[(size_t)(o * CC + c) * 9 + tap];
            }
            *(f16x8*)(wA_def + (size_t)(id2 * 64 + l) * 8) = v;
        }
    }
}

__device__ __forceinline__ f16x8 combine4(f16x8 p00, f16x8 p01, f16x8 p10, f16x8 p11,
                                          f16 h00, f16 h01, f16 h10, f16 h11) {
    const f16x8 W00 = {h00,h00,h00,h00,h00,h00,h00,h00};
    const f16x8 W01 = {h01,h01,h01,h01,h01,h01,h01,h01};
    const f16x8 W10 = {h10,h10,h10,h10,h10,h10,h10,h10};
    const f16x8 W11 = {h11,h11,h11,h11,h11,h11,h11,h11};
    return p00 * W00 + p01 * W01 + p10 * W10 + p11 * W11;
}

// ================= REAL KERNEL (round-9, proven correct, unchanged) =================
__global__ __launch_bounds__(128, 3) void deform_mfma(
    const f16* __restrict__ xt,
    const f16* __restrict__ wA_off,
    const float* __restrict__ offb,
    const f16* __restrict__ wA_def,
    const float* __restrict__ dbias,
    float* __restrict__ out)
{
    __shared__ __align__(16) char win[5 * 36 * 8 * 16];
    __shared__ float offs[18][32];

    const int tid = threadIdx.x;
    const int bid0 = blockIdx.x;
    const int bid = (bid0 & 7) * 256 + (bid0 >> 3);
    const int b = bid >> 9, row = (bid >> 2) & 127, px0 = (bid & 3) * 32;
    const int w = tid >> 6, l = tid & 63;
    const int pxs = l & 15, pxl = w * 16 + pxs, gpx = px0 + pxl, cg = l >> 4;

    #pragma unroll
    for (int it = 0; it < 12; ++it) {
        const int i = tid + it * 128;
        if (i < 5 * 36 * 8) {
            const int s = i / 288, rem = i - s * 288;
            const int xw = rem >> 3, ch8 = rem & 7;
            const int gy = row - 2 + s, gx = px0 - 2 + xw;
            f16x8 v = {};
            if (gy >= 0 && gy < HH && gx >= 0 && gx < WW)
                v = *(const f16x8*)(xt + xt_idx(b, gy, gx) + ch8 * 8);
            *(f16x8*)(win + ((s * 36 + xw) * 8 + (ch8 ^ ((xw + s) & 7))) * 16) = v;
        }
    }
    __syncthreads();

    {
        f32x4 oa0 = {0,0,0,0}, oa1 = {0,0,0,0};
        #pragma unroll
        for (int ks = 0; ks < 18; ++ks) {
            const int tap = ks >> 1, chalf = ks & 1;
            const int ky = tap / 3, kx = tap - ky * 3;
            const int s = 1 + ky;
            const int xw = pxl + 1 + kx;
            const int ch8 = chalf * 4 + cg;
            const int byte = ((s * 36 + xw) * 8 + (ch8 ^ ((xw + s) & 7))) * 16;
            const f16x8 bf = *(const f16x8*)(win + byte);
            const f16x8 a0 = *(const f16x8*)(wA_off + (size_t)((ks * 2 + 0) * 64 + l) * 8);
            const f16x8 a1 = *(const f16x8*)(wA_off + (size_t)((ks * 2 + 1) * 64 + l) * 8);
            oa0 = __builtin_amdgcn_mfma_f32_16x16x32_f16(a0, bf, oa0, 0, 0, 0);
            oa1 = __builtin_amdgcn_mfma_f32_16x16x32_f16(a1, bf, oa1, 0, 0, 0);
        }
        #pragma unroll
        for (int reg = 0; reg < 4; ++reg) {
            const int o0 = cg * 4 + reg;
            offs[o0][pxl] = oa0[reg] + offb[o0];
            const int o1 = o0 + 16;
            if (o1 < 18) offs[o1][pxl] = oa1[reg] + offb[o1];
        }
    }
    __syncthreads();

    int o00[9], o01[9], o10[9], o11[9];
    f16x2 hA[9], hB[9];
    unsigned okm = 0;
    #pragma unroll
    for (int t = 0; t < 9; ++t) {
        const int ky = t / 3, kx = t - ky * 3;
        const float dy = offs[2 * t][pxl], dx = offs[2 * t + 1][pxl];
        const float py  = (float)(row - 1 + ky) + dy;
        const float pxf = (float)(gpx - 1 + kx) + dx;
        const float y0f = floorf(py), x0f = floorf(pxf);
        const float wy = py - y0f, wx = pxf - x0f;
        const int y0 = (int)y0f, x0 = (int)x0f;
        const int y1 = y0 + 1, x1 = x0 + 1;
        const bool vy0 = (y0 >= 0) & (y0 < HH), vy1 = (y1 >= 0) & (y1 < HH);
        const bool vx0 = (x0 >= 0) & (x0 < WW), vx1 = (x1 >= 0) & (x1 < WW);
        hA[t][0] = (f16)((1.f - wy) * (1.f - wx) * (float)(vy0 & vx0));
        hA[t][1] = (f16)((1.f - wy) * wx         * (float)(vy0 & vx1));
        hB[t][0] = (f16)(wy * (1.f - wx)         * (float)(vy1 & vx0));
        hB[t][1] = (f16)(wy * wx                 * (float)(vy1 & vx1));
        const int cy0 = min(max(y0, 0), HH - 1), cy1 = min(max(y1, 0), HH - 1);
        const int cx0 = min(max(x0, 0), WW - 1), cx1 = min(max(x1, 0), WW - 1);
        const int s0 = cy0 - (row - 2), s1 = cy1 - (row - 2);
        const int u0 = cx0 - (px0 - 2), u1 = cx1 - (px0 - 2);
        const int ok = (s0 >= 0) & (s0 < 5) & (s1 >= 0) & (s1 < 5) &
                       (u0 >= 0) & (u0 < 36) & (u1 >= 0) & (u1 < 36);
        if (__all(ok)) okm |= (1u << t);
        const int s0c = min(max(s0, 0), 4), s1c = min(max(s1, 0), 4);
        const int u0c = min(max(u0, 0), 35), u1c = min(max(u1, 0), 35);
        o00[t] = ((s0c * 36 + u0c) * 8 + (cg ^ ((u0c + s0c) & 7))) * 16;
        o01[t] = ((s0c * 36 + u1c) * 8 + (cg ^ ((u1c + s0c) & 7))) * 16;
        o10[t] = ((s1c * 36 + u0c) * 8 + (cg ^ ((u0c + s1c) & 7))) * 16;
        o11[t] = ((s1c * 36 + u1c) * 8 + (cg ^ ((u1c + s1c) & 7))) * 16;
    }

    f32x4 acc0 = {0,0,0,0}, acc1 = {0,0,0,0}, acc2 = {0,0,0,0}, acc3 = {0,0,0,0};
    const f16* wbase = wA_def + (size_t)l * 8;

    if (okm == 0x1FFu) {
        #pragma unroll
        for (int j = 0; j < 18; ++j) {
            const int t = j >> 1, fl = (j & 1) << 6;
            const f16x8 p00 = *(const f16x8*)(win + (o00[t] ^ fl));
            const f16x8 p01 = *(const f16x8*)(win + (o01[t] ^ fl));
            const f16x8 p10 = *(const f16x8*)(win + (o10[t] ^ fl));
            const f16x8 p11 = *(const f16x8*)(win + (o11[t] ^ fl));
            const f16x8 bf = combine4(p00, p01, p10, p11,
                                      hA[t][0], hA[t][1], hB[t][0], hB[t][1]);
            const f16* wa = wbase + (size_t)j * 2048;
            acc0 = __builtin_amdgcn_mfma_f32_16x16x32_f16(*(const f16x8*)(wa + 0 * 512), bf, acc0, 0, 0, 0);
            acc1 = __builtin_amdgcn_mfma_f32_16x16x32_f16(*(const f16x8*)(wa + 1 * 512), bf, acc1, 0, 0, 0);
            acc2 = __builtin_amdgcn_mfma_f32_16x16x32_f16(*(const f16x8*)(wa + 2 * 512), bf, acc2, 0, 0, 0);
            acc3 = __builtin_amdgcn_mfma_f32_16x16x32_f16(*(const f16x8*)(wa + 3 * 512), bf, acc3, 0, 0, 0);
        }
    } else {
        #pragma unroll
        for (int t = 0; t < 9; ++t) {
            #pragma unroll
            for (int cpass = 0; cpass < 2; ++cpass) {
                const int flip = cpass << 6;
                f16x8 bf;
                if ((okm >> t) & 1) {
                    const f16x8 p00 = *(const f16x8*)(win + (o00[t] ^ flip));
                    const f16x8 p01 = *(const f16x8*)(win + (o01[t] ^ flip));
                    const f16x8 p10 = *(const f16x8*)(win + (o10[t] ^ flip));
                    const f16x8 p11 = *(const f16x8*)(win + (o11[t] ^ flip));
                    bf = combine4(p00, p01, p10, p11,
                                  hA[t][0], hA[t][1], hB[t][0], hB[t][1]);
                } else {
                    const int ky = t / 3, kx = t - ky * 3;
                    const float dy = offs[2 * t][pxl], dx = offs[2 * t + 1][pxl];
                    const float py  = (float)(row - 1 + ky) + dy;
                    const float pxf = (float)(gpx - 1 + kx) + dx;
                    const int y0 = (int)floorf(py), x0 = (int)floorf(pxf);
                    const int cy0 = min(max(y0, 0), HH - 1), cy1 = min(max(y0 + 1, 0), HH - 1);
                    const int cx0 = min(max(x0, 0), WW - 1), cx1 = min(max(x0 + 1, 0), WW - 1);
                    const int ch8 = cpass * 4 + cg;
                    const f16x8 p00 = *(const f16x8*)(xt + xt_idx(b, cy0, cx0) + ch8 * 8);
                    const f16x8 p01 = *(const f16x8*)(xt + xt_idx(b, cy0, cx1) + ch8 * 8);
                    const f16x8 p10 = *(const f16x8*)(xt + xt_idx(b, cy1, cx0) + ch8 * 8);
                    const f16x8 p11 = *(const f16x8*)(xt + xt_idx(b, cy1, cx1) + ch8 * 8);
                    bf = combine4(p00, p01, p10, p11,
                                  hA[t][0], hA[t][1], hB[t][0], hB[t][1]);
                }
                const f16* wa = wbase + (size_t)(t * 2 + cpass) * 2048;
                acc0 = __builtin_amdgcn_mfma_f32_16x16x32_f16(*(const f16x8*)(wa + 0 * 512), bf, acc0, 0, 0, 0);
                acc1 = __builtin_amdgcn_mfma_f32_16x16x32_f16(*(const f16x8*)(wa + 1 * 512), bf, acc1, 0, 0, 0);
                acc2 = __builtin_amdgcn_mfma_f32_16x16x32_f16(*(const f16x8*)(wa + 2 * 512), bf, acc2, 0, 0, 0);
                acc3 = __builtin_amdgcn_mfma_f32_16x16x32_f16(*(const f16x8*)(wa + 3 * 512), bf, acc3, 0, 0, 0);
            }
        }
    }

    #pragma unroll
    for (int mt = 0; mt < 4; ++mt) {
        const f32x4 a = (mt == 0) ? acc0 : (mt == 1) ? acc1 : (mt == 2) ? acc2 : acc3;
        #pragma unroll
        for (int reg = 0; reg < 4; ++reg) {
            const int o = mt * 16 + cg * 4 + reg;
            out[(((size_t)b * OO + o) * HH + row) * WW + gpx] = a[reg] + dbias[o];
        }
    }
}

// ================= ABLATION PROBES (write only to d_ws) =================
// MODE 0: window staging only          MODE 1: + phase-1 MFMA loop
// MODE 2: phase-2 gathers+combine+MFMA, constant A (no weight loads)
// MODE 3: MODE 2 + GLOBAL weight loads  MODE 4: MODE 2 + LDS-staged weights
template<int MODE, int REPS>
__global__ __launch_bounds__(128) void probe(const f16* __restrict__ xt,
                                             const f16* __restrict__ wA_off,
                                             const f16* __restrict__ wA_def,
                                             float* __restrict__ pout)
{
    __shared__ __align__(16) char win[5 * 36 * 8 * 16];   // 23040
    __shared__ __align__(16) char wlds[36 * 1024];        // 36864 (MODE 4)

    const int tid = threadIdx.x;
    const int bid0 = blockIdx.x;
    const int bid = (bid0 & 7) * 256 + (bid0 >> 3);
    const int b = bid >> 9, row = (bid >> 2) & 127, px0 = (bid & 3) * 32;
    const int w = tid >> 6, l = tid & 63;
    const int pxl = w * 16 + (l & 15), gpx = px0 + pxl, cg = l >> 4;

    float sink = 0.f;

    if (MODE == 0) {
        for (int rep = 0; rep < REPS; ++rep) {
            #pragma unroll
            for (int it = 0; it < 12; ++it) {
                const int i = tid + it * 128;
                if (i < 5 * 36 * 8) {
                    const int s = i / 288, rem = i - s * 288;
                    const int xw = rem >> 3, ch8 = rem & 7;
                    const int gy = min(max(row - 2 + s + (rep & 1), 0), HH - 1);
                    const int gx = min(max(px0 - 2 + xw, 0), WW - 1);
                    const f16x8 v = *(const f16x8*)(xt + xt_idx(b, gy, gx) + ch8 * 8);
                    *(f16x8*)(win + ((s * 36 + xw) * 8 + (ch8 ^ ((xw + s) & 7))) * 16) = v;
                }
            }
            __syncthreads();
            sink += *(const float*)(win + ((tid * 177 + rep * 16) & 23024 & ~15));
            __syncthreads();
        }
        pout[(size_t)bid0 * 128 + tid] = sink;
        return;
    }

    // stage once (all other modes)
    #pragma unroll
    for (int it = 0; it < 12; ++it) {
        const int i = tid + it * 128;
        if (i < 5 * 36 * 8) {
            const int s = i / 288, rem = i - s * 288;
            const int xw = rem >> 3, ch8 = rem & 7;
            const int gy = min(max(row - 2 + s, 0), HH - 1);
            const int gx = min(max(px0 - 2 + xw, 0), WW - 1);
            const f16x8 v = *(const f16x8*)(xt + xt_idx(b, gy, gx) + ch8 * 8);
            *(f16x8*)(win + ((s * 36 + xw) * 8 + (ch8 ^ ((xw + s) & 7))) * 16) = v;
        }
    }
    if (MODE == 4) {
        #pragma unroll
        for (int it = 0; it < 18; ++it) {
            const int i = tid + it * 128;
            *(f16x8*)(wlds + i * 16) = *(const f16x8*)((const char*)wA_def + (size_t)i * 16);
        }
    }
    __syncthreads();

    if (MODE == 1) {
        f32x4 oa0 = {0,0,0,0}, oa1 = {0,0,0,0};
        for (int rep = 0; rep < REPS; ++rep) {
            #pragma unroll
            for (int ks = 0; ks < 18; ++ks) {
                const int tap = ks >> 1, chalf = ks & 1;
                const int ky = tap / 3, kx = tap - ky * 3;
                const int s = 1 + ky;
                const int xw = pxl + 1 + kx;
                const int ch8 = chalf * 4 + cg;
                const int byte = (((s * 36 + xw) * 8 + (ch8 ^ ((xw + s) & 7))) * 16) ^ ((rep & 1) << 7);
                const f16x8 bf = *(const f16x8*)(win + byte);
                const int e = ((ks + rep) % 18) * 2;
                const f16x8 a0 = *(const f16x8*)(wA_off + (size_t)((e + 0) * 64 + l) * 8);
                const f16x8 a1 = *(const f16x8*)(wA_off + (size_t)((e + 1) * 64 + l) * 8);
                oa0 = __builtin_amdgcn_mfma_f32_16x16x32_f16(a0, bf, oa0, 0, 0, 0);
                oa1 = __builtin_amdgcn_mfma_f32_16x16x32_f16(a1, bf, oa1, 0, 0, 0);
            }
        }
        pout[(size_t)bid0 * 128 + tid] = oa0[0] + oa1[1];
        return;
    }

    // MODE 2/3/4: synthetic taps (same address pattern as real kernel, window-clamped)
    int o00[9], o01[9], o10[9], o11[9];
    f16x2 hA[9], hB[9];
    #pragma unroll
    for (int t = 0; t < 9; ++t) {
        const int ky = t / 3, kx = t - ky * 3;
        const float dy = 0.1f * (float)(((gpx * 13 + row * 7 + t * 5) & 7) - 3);
        const float dx = 0.1f * (float)(((gpx * 11 + row * 3 + t * 9) & 7) - 3);
        const float py  = (float)(row - 1 + ky) + dy;
        const float pxf = (float)(gpx - 1 + kx) + dx;
        const float y0f = floorf(py), x0f = floorf(pxf);
        const float wy = py - y0f, wx = pxf - x0f;
        const int y0 = (int)y0f, x0 = (int)x0f;
        hA[t][0] = (f16)((1.f - wy) * (1.f - wx));
        hA[t][1] = (f16)((1.f - wy) * wx);
        hB[t][0] = (f16)(wy * (1.f - wx));
        hB[t][1] = (f16)(wy * wx);
        const int s0 = min(max(y0 - (row - 2), 0), 4),  s1 = min(max(y0 + 1 - (row - 2), 0), 4);
        const int u0 = min(max(x0 - (px0 - 2), 0), 35), u1 = min(max(x0 + 1 - (px0 - 2), 0), 35);
        o00[t] = ((s0 * 36 + u0) * 8 + (cg ^ ((u0 + s0) & 7))) * 16;
        o01[t] = ((s0 * 36 + u1) * 8 + (cg ^ ((u1 + s0) & 7))) * 16;
        o10[t] = ((s1 * 36 + u0) * 8 + (cg ^ ((u0 + s1) & 7))) * 16;
        o11[t] = ((s1 * 36 + u1) * 8 + (cg ^ ((u1 + s1) & 7))) * 16;
    }

    f32x4 acc0 = {0,0,0,0}, acc1 = {0,0,0,0}, acc2 = {0,0,0,0}, acc3 = {0,0,0,0};
    f16x8 afix;
    #pragma unroll
    for (int i = 0; i < 8; ++i) afix[i] = (f16)(0.01f * (float)(i + cg));
    const f16* wbase = wA_def + (size_t)l * 8;

    for (int rep = 0; rep < REPS; ++rep) {
        #pragma unroll
        for (int j = 0; j < 18; ++j) {
            const int t = j >> 1;
            const int fl = ((j & 1) << 6) ^ ((rep & 1) << 7);
            const f16x8 p00 = *(const f16x8*)(win + (o00[t] ^ fl));
            const f16x8 p01 = *(const f16x8*)(win + (o01[t] ^ fl));
            const f16x8 p10 = *(const f16x8*)(win + (o10[t] ^ fl));
            const f16x8 p11 = *(const f16x8*)(win + (o11[t] ^ fl));
            const f16x8 bf = combine4(p00, p01, p10, p11,
                                      hA[t][0], hA[t][1], hB[t][0], hB[t][1]);
            f16x8 A0, A1, A2, A3;
            if (MODE == 2) {
                A0 = afix; A1 = afix; A2 = afix; A3 = afix;
            } else if (MODE == 3) {
                const f16* wa = wbase + (size_t)(((j + rep * 7) % 36) * 2048);
                A0 = *(const f16x8*)(wa + 0 * 512);
                A1 = *(const f16x8*)(wa + 1 * 512);
                A2 = *(const f16x8*)(wa + 2 * 512);
                A3 = *(const f16x8*)(wa + 3 * 512);
            } else {
                const char* wa = wlds + ((j + rep) % 9) * 4096 + l * 16;
                A0 = *(const f16x8*)(wa + 0 * 1024);
                A1 = *(const f16x8*)(wa + 1 * 1024);
                A2 = *(const f16x8*)(wa + 2 * 1024);
                A3 = *(const f16x8*)(wa + 3 * 1024);
            }
            acc0 = __builtin_amdgcn_mfma_f32_16x16x32_f16(A0, bf, acc0, 0, 0, 0);
            acc1 = __builtin_amdgcn_mfma_f32_16x16x32_f16(A1, bf, acc1, 0, 0, 0);
            acc2 = __builtin_amdgcn_mfma_f32_16x16x32_f16(A2, bf, acc2, 0, 0, 0);
            acc3 = __builtin_amdgcn_mfma_f32_16x16x32_f16(A3, bf, acc3, 0, 0, 0);
        }
    }
    pout[(size_t)bid0 * 128 + tid] = acc0[0] + acc1[1] + acc2[2] + acc3[3] + sink;
}

extern "C" void kernel_launch(void* const* d_in, const int* in_sizes, int n_in,
                              void* d_out, int out_size, void* d_ws, size_t ws_size,
                              hipStream_t stream) {
    const float* x     = (const float*)d_in[0];
    const float* offw  = (const float*)d_in[1];
    const float* offb  = (const float*)d_in[2];
    const float* dw    = (const float*)d_in[3];
    const float* dbias = (const float*)d_in[4];
    float* out = (float*)d_out;

    const size_t XT_BYTES    = (size_t)BB * HH * WW * CC * sizeof(f16);
    const size_t WAOFF_BYTES = 36 * 64 * 8 * sizeof(f16);

    f16* xt     = (f16*)d_ws;
    f16* wa_off = (f16*)((char*)d_ws + XT_BYTES);
    f16* wa_def = (f16*)((char*)d_ws + XT_BYTES + WAOFF_BYTES);
    (void)in_sizes; (void)n_in; (void)out_size;

    prep_all<<<512 + 27, 256, 0, stream>>>(x, offw, dw, xt, wa_off, wa_def);
    deform_mfma<<<BB * HH * 4, 128, 0, stream>>>(xt, wa_off, offb, wa_def, dbias, out);

    if (ws_size >= (size_t)48 << 20) {
        float* p0 = (float*)((char*)d_ws + ((size_t)16 << 20));
        float* p1 = p0 + 2048 * 128;
        float* p2 = p1 + 2048 * 128;
        float* p3 = p2 + 2048 * 128;
        float* p4 = p3 + 2048 * 128;
        probe<0, 16><<<2048, 128, 0, stream>>>(xt, wa_off, wa_def, p0);
        probe<1,  8><<<2048, 128, 0, stream>>>(xt, wa_off, wa_def, p1);
        probe<2,  8><<<2048, 128, 0, stream>>>(xt, wa_off, wa_def, p2);
        probe<3,  8><<<2048, 128, 0, stream>>>(xt, wa_off, wa_def, p3);
        probe<4,  8><<<2048, 128, 0, stream>>>(xt, wa_off, wa_def, p4);
    }
}

// Round 13
// 59.482 us; speedup vs baseline: 7.1477x; 7.1477x over previous
//
#include <hip/hip_runtime.h>

#define BB 4
#define CC 64
#define HH 128
#define WW 128
#define OO 64
#define HWs (HH*WW)

typedef _Float16 f16;
typedef _Float16 f16x8 __attribute__((ext_vector_type(8)));
typedef _Float16 f16x2 __attribute__((ext_vector_type(2)));
typedef float f32x4 __attribute__((ext_vector_type(4)));

__device__ __forceinline__ size_t xt_idx(int b, int y, int x) {
    return (((size_t)b * HH + y) * WW + x) * CC;
}

// ---------- fused prep: x transpose (NCHW f32 -> NHWC f16) + weight packing ----------
__global__ __launch_bounds__(256) void prep_all(const float* __restrict__ x,
                                                const float* __restrict__ offw,
                                                const float* __restrict__ dw,
                                                f16* __restrict__ xt,
                                                f16* __restrict__ wA_off,
                                                f16* __restrict__ wA_def) {
    const int bid = blockIdx.x;
    const int tid = threadIdx.x;
    if (bid < 512) {
        const int b = bid >> 7, y = bid & 127;
        const int px = tid & 127, half = tid >> 7;
        const float* src = x + (size_t)b * CC * HWs + (size_t)half * 32 * HWs + y * WW + px;
        f16* dst = xt + xt_idx(b, y, px) + half * 32;
        #pragma unroll
        for (int cg = 0; cg < 4; ++cg) {
            f16x8 v;
            #pragma unroll
            for (int j = 0; j < 8; ++j)
                v[j] = (f16)src[(size_t)(cg * 8 + j) * HWs];
            *(f16x8*)(dst + cg * 8) = v;
        }
    } else {
        const int t = (bid - 512) * 256 + tid;
        const int l = t & 63;
        const int idx = t >> 6;
        f16x8 v;
        if (idx < 36) {
            const int mt = idx & 1, ks = idx >> 1;
            const int o = mt * 16 + (l & 15);
            const int tap = ks >> 1, ky = tap / 3, kx = tap % 3;
            #pragma unroll
            for (int i = 0; i < 8; ++i) {
                const int c = (ks & 1) * 32 + (l >> 4) * 8 + i;
                v[i] = (o < 18) ? (f16)offw[((o * CC + c) * 3 + ky) * 3 + kx] : (f16)0.f;
            }
            *(f16x8*)(wA_off + (size_t)(idx * 64 + l) * 8) = v;
        } else if (idx < 108) {
            const int id2 = idx - 36;
            const int mt = id2 & 3, ks = (id2 >> 2) & 1, tap = id2 >> 3;
            const int o = mt * 16 + (l & 15);
            #pragma unroll
            for (int i = 0; i < 8; ++i) {
                const int c = ks * 32 + (l >> 4) * 8 + i;
                v[i] = (f16)dw[(size_t)(o * CC + c) * 9 + tap];
            }
            *(f16x8*)(wA_def + (size_t)(id2 * 64 + l) * 8) = v;
        }
    }
}

__device__ __forceinline__ f16x8 combine4(f16x8 p00, f16x8 p01, f16x8 p10, f16x8 p11,
                                          f16 h00, f16 h01, f16 h10, f16 h11) {
    const f16x8 W00 = {h00,h00,h00,h00,h00,h00,h00,h00};
    const f16x8 W01 = {h01,h01,h01,h01,h01,h01,h01,h01};
    const f16x8 W10 = {h10,h10,h10,h10,h10,h10,h10,h10};
    const f16x8 W11 = {h11,h11,h11,h11,h11,h11,h11,h11};
    return p00 * W00 + p01 * W01 + p10 * W10 + p11 * W11;
}

// ---------- main: 64px blocks, weight-amortized decomposition ----------
// Phase 1: wave w = (ohalf = w>>1, px-half = w&1): 1 A-load -> 2 B-frags.
// Phase 2: wave w = output tile mt; 1 weight load -> 4 B-frags (all 64 px).
__global__ __launch_bounds__(256, 3) void deform_mfma(
    const f16* __restrict__ xt,
    const f16* __restrict__ wA_off,
    const float* __restrict__ offb,
    const f16* __restrict__ wA_def,
    const float* __restrict__ dbias,
    float* __restrict__ out)
{
    // [5 rows][68 px][8 chunks of 16B (8 f16 ch)], chunk slot XOR-swizzled
    __shared__ __align__(16) char win[5 * 68 * 8 * 16];   // 43520 B
    __shared__ float offs[18][64];                         // 4608 B -> 48128 total

    const int tid = threadIdx.x;
    const int bid0 = blockIdx.x;
    const int bid = (bid0 & 7) * 128 + (bid0 >> 3);   // XCD swizzle (1024 % 8 == 0)
    const int b = bid >> 8, row = (bid >> 1) & 127, px0 = (bid & 1) * 64;
    const int w = tid >> 6, l = tid & 63;
    const int pxs = l & 15, cg = l >> 4;

    // ---- stage: rows row-2..row+2, x in [px0-2, px0+65], all 64c, zero-padded ----
    #pragma unroll
    for (int it = 0; it < 11; ++it) {
        const int i = tid + it * 256;
        if (i < 5 * 68 * 8) {
            const int s = i / 544, rem = i - s * 544;
            const int xw = rem >> 3, ch8 = rem & 7;
            const int gy = row - 2 + s, gx = px0 - 2 + xw;
            f16x8 v = {};
            if (gy >= 0 && gy < HH && gx >= 0 && gx < WW)
                v = *(const f16x8*)(xt + xt_idx(b, gy, gx) + ch8 * 8);
            *(f16x8*)(win + ((s * 68 + xw) * 8 + (ch8 ^ ((xw + s) & 7))) * 16) = v;
        }
    }
    __syncthreads();

    // ---- phase 1: offset conv; 1 A-load per ks feeds 2 B-frags ----
    {
        const int ohalf = w >> 1, pxh = w & 1;
        f32x4 oaA = {0,0,0,0}, oaB = {0,0,0,0};
        #pragma unroll
        for (int ks = 0; ks < 18; ++ks) {
            const int tap = ks >> 1, khalf = ks & 1;
            const int ky = tap / 3, kx = tap - ky * 3;
            const int s = 1 + ky;
            const int ch8 = khalf * 4 + cg;
            const f16x8 a = *(const f16x8*)(wA_off + (size_t)((ks * 2 + ohalf) * 64 + l) * 8);
            const int xwA = pxh * 32 + pxs + 1 + kx;
            const int xwB = xwA + 16;
            const f16x8 bfA = *(const f16x8*)(win + ((s * 68 + xwA) * 8 + (ch8 ^ ((xwA + s) & 7))) * 16);
            const f16x8 bfB = *(const f16x8*)(win + ((s * 68 + xwB) * 8 + (ch8 ^ ((xwB + s) & 7))) * 16);
            oaA = __builtin_amdgcn_mfma_f32_16x16x32_f16(a, bfA, oaA, 0, 0, 0);
            oaB = __builtin_amdgcn_mfma_f32_16x16x32_f16(a, bfB, oaB, 0, 0, 0);
        }
        #pragma unroll
        for (int reg = 0; reg < 4; ++reg) {
            const int ch = ohalf * 16 + cg * 4 + reg;
            if (ch < 18) {
                offs[ch][pxh * 32 + pxs]      = oaA[reg] + offb[ch];
                offs[ch][pxh * 32 + 16 + pxs] = oaB[reg] + offb[ch];
            }
        }
    }
    __syncthreads();   // offs ready; win read-only from here

    // ---- phase 2: wave w = output tile; per (t,cpass): 1 weight load, 4 MFMA ----
    f32x4 acc[4] = {{0,0,0,0},{0,0,0,0},{0,0,0,0},{0,0,0,0}};

    #pragma unroll
    for (int t = 0; t < 9; ++t) {
        const int ky = t / 3, kx = t - ky * 3;
        int o00[4], o01[4], o10[4], o11[4];
        f16x2 hA[4], hB[4];
        int okbits = 0;
        #pragma unroll
        for (int q = 0; q < 4; ++q) {
            const int pq = q * 16 + pxs;
            const float dy = offs[2 * t][pq], dx = offs[2 * t + 1][pq];
            const float py  = (float)(row - 1 + ky) + dy;
            const float pxf = (float)(px0 + pq - 1 + kx) + dx;
            const float y0f = floorf(py), x0f = floorf(pxf);
            const float wy = py - y0f, wx = pxf - x0f;
            const int y0 = (int)y0f, x0 = (int)x0f;
            const int y1 = y0 + 1, x1 = x0 + 1;
            const bool vy0 = (y0 >= 0) & (y0 < HH), vy1 = (y1 >= 0) & (y1 < HH);
            const bool vx0 = (x0 >= 0) & (x0 < WW), vx1 = (x1 >= 0) & (x1 < WW);
            hA[q][0] = (f16)((1.f - wy) * (1.f - wx) * (float)(vy0 & vx0));
            hA[q][1] = (f16)((1.f - wy) * wx         * (float)(vy0 & vx1));
            hB[q][0] = (f16)(wy * (1.f - wx)         * (float)(vy1 & vx0));
            hB[q][1] = (f16)(wy * wx                 * (float)(vy1 & vx1));
            const int cy0 = min(max(y0, 0), HH - 1), cy1 = min(max(y1, 0), HH - 1);
            const int cx0 = min(max(x0, 0), WW - 1), cx1 = min(max(x1, 0), WW - 1);
            const int s0 = cy0 - (row - 2), s1 = cy1 - (row - 2);
            const int u0 = cx0 - (px0 - 2), u1 = cx1 - (px0 - 2);
            const int ok = (s0 >= 0) & (s0 < 5) & (s1 >= 0) & (s1 < 5) &
                           (u0 >= 0) & (u0 < 68) & (u1 >= 0) & (u1 < 68);
            if (__all(ok)) okbits |= (1 << q);
            const int s0c = min(max(s0, 0), 4), s1c = min(max(s1, 0), 4);
            const int u0c = min(max(u0, 0), 67), u1c = min(max(u1, 0), 67);
            o00[q] = ((s0c * 68 + u0c) * 8 + (cg ^ ((u0c + s0c) & 7))) * 16;
            o01[q] = ((s0c * 68 + u1c) * 8 + (cg ^ ((u1c + s0c) & 7))) * 16;
            o10[q] = ((s1c * 68 + u0c) * 8 + (cg ^ ((u0c + s1c) & 7))) * 16;
            o11[q] = ((s1c * 68 + u1c) * 8 + (cg ^ ((u1c + s1c) & 7))) * 16;
        }

        #pragma unroll
        for (int cpass = 0; cpass < 2; ++cpass) {
            const int flip = cpass << 6;
            const f16x8 wv = *(const f16x8*)(wA_def +
                               (size_t)(((t * 2 + cpass) * 4 + w) * 64 + l) * 8);
            #pragma unroll
            for (int q = 0; q < 4; ++q) {
                f16x8 bf;
                if ((okbits >> q) & 1) {
                    const f16x8 p00 = *(const f16x8*)(win + (o00[q] ^ flip));
                    const f16x8 p01 = *(const f16x8*)(win + (o01[q] ^ flip));
                    const f16x8 p10 = *(const f16x8*)(win + (o10[q] ^ flip));
                    const f16x8 p11 = *(const f16x8*)(win + (o11[q] ^ flip));
                    bf = combine4(p00, p01, p10, p11,
                                  hA[q][0], hA[q][1], hB[q][0], hB[q][1]);
                } else {
                    // rare: recompute clamped coords, gather from global xt
                    const int pq = q * 16 + pxs;
                    const float dy = offs[2 * t][pq], dx = offs[2 * t + 1][pq];
                    const float py  = (float)(row - 1 + ky) + dy;
                    const float pxf = (float)(px0 + pq - 1 + kx) + dx;
                    const int y0 = (int)floorf(py), x0 = (int)floorf(pxf);
                    const int cy0 = min(max(y0, 0), HH - 1), cy1 = min(max(y0 + 1, 0), HH - 1);
                    const int cx0 = min(max(x0, 0), WW - 1), cx1 = min(max(x0 + 1, 0), WW - 1);
                    const int ch8 = cpass * 4 + cg;
                    const f16x8 p00 = *(const f16x8*)(xt + xt_idx(b, cy0, cx0) + ch8 * 8);
                    const f16x8 p01 = *(const f16x8*)(xt + xt_idx(b, cy0, cx1) + ch8 * 8);
                    const f16x8 p10 = *(const f16x8*)(xt + xt_idx(b, cy1, cx0) + ch8 * 8);
                    const f16x8 p11 = *(const f16x8*)(xt + xt_idx(b, cy1, cx1) + ch8 * 8);
                    bf = combine4(p00, p01, p10, p11,
                                  hA[q][0], hA[q][1], hB[q][0], hB[q][1]);
                }
                acc[q] = __builtin_amdgcn_mfma_f32_16x16x32_f16(wv, bf, acc[q], 0, 0, 0);
            }
        }
    }

    // ---- epilogue: wave w stores oc tile w*16.., 4 px-tiles ----
    #pragma unroll
    for (int reg = 0; reg < 4; ++reg) {
        const int o = w * 16 + cg * 4 + reg;
        const float bias = dbias[o];
        float* op = out + (((size_t)b * OO + o) * HH + row) * WW + px0 + pxs;
        #pragma unroll
        for (int q = 0; q < 4; ++q)
            op[q * 16] = acc[q][reg] + bias;
    }
}

extern "C" void kernel_launch(void* const* d_in, const int* in_sizes, int n_in,
                              void* d_out, int out_size, void* d_ws, size_t ws_size,
                              hipStream_t stream) {
    const float* x     = (const float*)d_in[0];
    const float* offw  = (const float*)d_in[1];
    const float* offb  = (const float*)d_in[2];
    const float* dw    = (const float*)d_in[3];
    const float* dbias = (const float*)d_in[4];
    float* out = (float*)d_out;

    const size_t XT_BYTES    = (size_t)BB * HH * WW * CC * sizeof(f16);   // 8 MiB
    const size_t WAOFF_BYTES = 36 * 64 * 8 * sizeof(f16);

    f16* xt     = (f16*)d_ws;
    f16* wa_off = (f16*)((char*)d_ws + XT_BYTES);
    f16* wa_def = (f16*)((char*)d_ws + XT_BYTES + WAOFF_BYTES);
    (void)ws_size; (void)in_sizes; (void)n_in; (void)out_size;

    prep_all<<<512 + 27, 256, 0, stream>>>(x, offw, dw, xt, wa_off, wa_def);
    deform_mfma<<<BB * HH * 2, 256, 0, stream>>>(xt, wa_off, offb, wa_def, dbias, out);
}

// Round 14
// 39.402 us; speedup vs baseline: 10.7902x; 1.5096x over previous
//
#include <hip/hip_runtime.h>

#define BB 4
#define CC 64
#define HH 128
#define WW 128
#define OO 64
#define HWs (HH*WW)
#define R9 9
#define XW 37

typedef _Float16 f16;
typedef _Float16 f16x8 __attribute__((ext_vector_type(8)));
typedef _Float16 f16x2 __attribute__((ext_vector_type(2)));
typedef float f32x4 __attribute__((ext_vector_type(4)));

__device__ __forceinline__ size_t xt_idx(int b, int y, int x) {
    return (((size_t)b * HH + y) * WW + x) * CC;
}

// ---------- fused prep: x transpose (NCHW f32 -> NHWC f16) + weight packing ----------
__global__ __launch_bounds__(256) void prep_all(const float* __restrict__ x,
                                                const float* __restrict__ offw,
                                                const float* __restrict__ dw,
                                                f16* __restrict__ xt,
                                                f16* __restrict__ wA_off,
                                                f16* __restrict__ wA_def) {
    const int bid = blockIdx.x;
    const int tid = threadIdx.x;
    if (bid < 512) {
        const int b = bid >> 7, y = bid & 127;
        const int px = tid & 127, half = tid >> 7;
        const float* src = x + (size_t)b * CC * HWs + (size_t)half * 32 * HWs + y * WW + px;
        f16* dst = xt + xt_idx(b, y, px) + half * 32;
        #pragma unroll
        for (int cg = 0; cg < 4; ++cg) {
            f16x8 v;
            #pragma unroll
            for (int j = 0; j < 8; ++j)
                v[j] = (f16)src[(size_t)(cg * 8 + j) * HWs];
            *(f16x8*)(dst + cg * 8) = v;
        }
    } else {
        const int t = (bid - 512) * 256 + tid;
        const int l = t & 63;
        const int idx = t >> 6;
        f16x8 v;
        if (idx < 36) {
            const int mt = idx & 1, ks = idx >> 1;
            const int o = mt * 16 + (l & 15);
            const int tap = ks >> 1, ky = tap / 3, kx = tap % 3;
            #pragma unroll
            for (int i = 0; i < 8; ++i) {
                const int c = (ks & 1) * 32 + (l >> 4) * 8 + i;
                v[i] = (o < 18) ? (f16)offw[((o * CC + c) * 3 + ky) * 3 + kx] : (f16)0.f;
            }
            *(f16x8*)(wA_off + (size_t)(idx * 64 + l) * 8) = v;
        } else if (idx < 108) {
            const int id2 = idx - 36;
            const int mt = id2 & 3, ks = (id2 >> 2) & 1, tap = id2 >> 3;
            const int o = mt * 16 + (l & 15);
            #pragma unroll
            for (int i = 0; i < 8; ++i) {
                const int c = ks * 32 + (l >> 4) * 8 + i;
                v[i] = (f16)dw[(size_t)(o * CC + c) * 9 + tap];
            }
            *(f16x8*)(wA_def + (size_t)(id2 * 64 + l) * 8) = v;
        }
    }
}

__device__ __forceinline__ f16x8 combine4(f16x8 p00, f16x8 p01, f16x8 p10, f16x8 p11,
                                          f16 h00, f16 h01, f16 h10, f16 h11) {
    const f16x8 W00 = {h00,h00,h00,h00,h00,h00,h00,h00};
    const f16x8 W01 = {h01,h01,h01,h01,h01,h01,h01,h01};
    const f16x8 W10 = {h10,h10,h10,h10,h10,h10,h10,h10};
    const f16x8 W11 = {h11,h11,h11,h11,h11,h11,h11,h11};
    return p00 * W00 + p01 * W01 + p10 * W10 + p11 * W11;
}

// ---------- main: 4-row x 32-px blocks, ALL weights + window in LDS ----------
// 512 threads = 8 waves = (4 rows) x (2 px-tiles); each wave: 16 px, all 4 mt.
__global__ __launch_bounds__(512) void deform_mfma(
    const f16* __restrict__ xt,
    const f16* __restrict__ wA_off,
    const float* __restrict__ offb,
    const f16* __restrict__ wA_def,
    const float* __restrict__ dbias,
    float* __restrict__ out)
{
    extern __shared__ __align__(16) char lds[];
    char*  wdef_l = lds;                          // 73728 B
    char*  woff_l = lds + 73728;                  // 36864 B
    char*  winp   = lds + 110592;                 // R9*XW*8*16 = 42624 B
    float* offs   = (float*)(lds + 153216);       // [18][128] f32 = 9216 -> 162432 B

    const int tid = threadIdx.x;
    const int bid0 = blockIdx.x;
    const int bid = (bid0 & 7) * 64 + (bid0 >> 3);   // XCD swizzle (512 % 8 == 0)
    const int b  = bid >> 7;                // 128 blocks per batch
    const int rg = (bid >> 2) & 31;
    const int pg = bid & 3;
    const int r0 = rg * 4, px0 = pg * 32;

    const int wid = tid >> 6, l = tid & 63;
    const int ri = wid >> 1, pt = wid & 1;
    const int pxs = l & 15, cg = l >> 4;
    const int pxl = pt * 16 + pxs;          // 0..31
    const int row = r0 + ri;
    const int gpx = px0 + pxl;
    const int slot = ri * 32 + pxl;         // 0..127

    // ---- stage weights into LDS (linear, coalesced) ----
    #pragma unroll
    for (int it = 0; it < 9; ++it) {
        const int i = tid + it * 512;       // < 4608
        *(f16x8*)(wdef_l + i * 16) = *(const f16x8*)((const char*)wA_def + (size_t)i * 16);
    }
    #pragma unroll
    for (int it = 0; it < 5; ++it) {
        const int i = tid + it * 512;
        if (i < 2304)
            *(f16x8*)(woff_l + i * 16) = *(const f16x8*)((const char*)wA_off + (size_t)i * 16);
    }
    // ---- stage window rows r0-2..r0+6, x in [px0-2, px0+34], zero-padded ----
    #pragma unroll
    for (int it = 0; it < 6; ++it) {
        const int i = tid + it * 512;
        if (i < R9 * XW * 8) {
            const int s = i / (XW * 8), rem = i - s * (XW * 8);
            const int xw = rem >> 3, ch8 = rem & 7;
            const int gy = r0 - 2 + s, gx = px0 - 2 + xw;
            f16x8 v = {};
            if (gy >= 0 && gy < HH && gx >= 0 && gx < WW)
                v = *(const f16x8*)(xt + xt_idx(b, gy, gx) + ch8 * 8);
            *(f16x8*)(winp + ((s * XW + xw) * 8 + (ch8 ^ ((xw + s) & 7))) * 16) = v;
        }
    }
    __syncthreads();

    // ---- phase 1: offset conv for (row, px-tile), weights from LDS ----
    {
        f32x4 oa0 = {0,0,0,0}, oa1 = {0,0,0,0};
        #pragma unroll
        for (int ks = 0; ks < 18; ++ks) {
            const int tap = ks >> 1, chalf = ks & 1;
            const int ky = tap / 3, kx = tap - ky * 3;
            const int s = ri + 1 + ky;              // in [1,6]
            const int xw = pxl + 1 + kx;            // in [1,34]
            const int ch8 = chalf * 4 + cg;
            const f16x8 bf = *(const f16x8*)(winp + ((s * XW + xw) * 8 + (ch8 ^ ((xw + s) & 7))) * 16);
            const f16x8 a0 = *(const f16x8*)(woff_l + ((ks * 2 + 0) * 64 + l) * 16);
            const f16x8 a1 = *(const f16x8*)(woff_l + ((ks * 2 + 1) * 64 + l) * 16);
            oa0 = __builtin_amdgcn_mfma_f32_16x16x32_f16(a0, bf, oa0, 0, 0, 0);
            oa1 = __builtin_amdgcn_mfma_f32_16x16x32_f16(a1, bf, oa1, 0, 0, 0);
        }
        #pragma unroll
        for (int reg = 0; reg < 4; ++reg) {
            const int c0 = cg * 4 + reg;
            offs[c0 * 128 + slot] = oa0[reg] + offb[c0];
            const int c1 = c0 + 16;
            if (c1 < 18) offs[c1 * 128 + slot] = oa1[reg] + offb[c1];
        }
    }
    __syncthreads();   // offs final; win/weights read-only from here

    // ---- tap precompute: window covers the full tap reach now ----
    int o00[9], o01[9], o10[9], o11[9];
    f16x2 hA[9], hB[9];
    unsigned okm = 0;
    #pragma unroll
    for (int t = 0; t < 9; ++t) {
        const int ky = t / 3, kx = t - ky * 3;
        const float dy = offs[(2 * t) * 128 + slot], dx = offs[(2 * t + 1) * 128 + slot];
        const float py  = (float)(row - 1 + ky) + dy;
        const float pxf = (float)(gpx - 1 + kx) + dx;
        const float y0f = floorf(py), x0f = floorf(pxf);
        const float wy = py - y0f, wx = pxf - x0f;
        const int y0 = (int)y0f, x0 = (int)x0f;
        const int y1 = y0 + 1, x1 = x0 + 1;
        const bool vy0 = (y0 >= 0) & (y0 < HH), vy1 = (y1 >= 0) & (y1 < HH);
        const bool vx0 = (x0 >= 0) & (x0 < WW), vx1 = (x1 >= 0) & (x1 < WW);
        hA[t][0] = (f16)((1.f - wy) * (1.f - wx) * (float)(vy0 & vx0));
        hA[t][1] = (f16)((1.f - wy) * wx         * (float)(vy0 & vx1));
        hB[t][0] = (f16)(wy * (1.f - wx)         * (float)(vy1 & vx0));
        hB[t][1] = (f16)(wy * wx                 * (float)(vy1 & vx1));
        const int cy0 = min(max(y0, 0), HH - 1), cy1 = min(max(y1, 0), HH - 1);
        const int cx0 = min(max(x0, 0), WW - 1), cx1 = min(max(x1, 0), WW - 1);
        const int s0 = cy0 - (r0 - 2), s1 = cy1 - (r0 - 2);
        const int u0 = cx0 - (px0 - 2), u1 = cx1 - (px0 - 2);
        const int ok = (s0 >= 0) & (s0 < R9) & (s1 >= 0) & (s1 < R9) &
                       (u0 >= 0) & (u0 < XW) & (u1 >= 0) & (u1 < XW);
        if (__all(ok)) okm |= (1u << t);
        const int s0c = min(max(s0, 0), R9 - 1), s1c = min(max(s1, 0), R9 - 1);
        const int u0c = min(max(u0, 0), XW - 1), u1c = min(max(u1, 0), XW - 1);
        o00[t] = ((s0c * XW + u0c) * 8 + (cg ^ ((u0c + s0c) & 7))) * 16;
        o01[t] = ((s0c * XW + u1c) * 8 + (cg ^ ((u1c + s0c) & 7))) * 16;
        o10[t] = ((s1c * XW + u0c) * 8 + (cg ^ ((u0c + s1c) & 7))) * 16;
        o11[t] = ((s1c * XW + u1c) * 8 + (cg ^ ((u1c + s1c) & 7))) * 16;
    }

    f32x4 acc0 = {0,0,0,0}, acc1 = {0,0,0,0}, acc2 = {0,0,0,0}, acc3 = {0,0,0,0};

    if (okm == 0x1FFu) {
        // ---- FAST PATH (now the true common case): all-LDS, branch-free ----
        #pragma unroll
        for (int j = 0; j < 18; ++j) {
            const int t = j >> 1, fl = (j & 1) << 6;
            const f16x8 p00 = *(const f16x8*)(winp + (o00[t] ^ fl));
            const f16x8 p01 = *(const f16x8*)(winp + (o01[t] ^ fl));
            const f16x8 p10 = *(const f16x8*)(winp + (o10[t] ^ fl));
            const f16x8 p11 = *(const f16x8*)(winp + (o11[t] ^ fl));
            const f16x8 bf = combine4(p00, p01, p10, p11,
                                      hA[t][0], hA[t][1], hB[t][0], hB[t][1]);
            const char* wa = wdef_l + ((j * 4) * 64 + l) * 16;
            acc0 = __builtin_amdgcn_mfma_f32_16x16x32_f16(*(const f16x8*)(wa + 0 * 1024), bf, acc0, 0, 0, 0);
            acc1 = __builtin_amdgcn_mfma_f32_16x16x32_f16(*(const f16x8*)(wa + 1 * 1024), bf, acc1, 0, 0, 0);
            acc2 = __builtin_amdgcn_mfma_f32_16x16x32_f16(*(const f16x8*)(wa + 2 * 1024), bf, acc2, 0, 0, 0);
            acc3 = __builtin_amdgcn_mfma_f32_16x16x32_f16(*(const f16x8*)(wa + 3 * 1024), bf, acc3, 0, 0, 0);
        }
    } else {
        // ---- SLOW PATH: per-tap wave-uniform fallback to global gather ----
        #pragma unroll
        for (int t = 0; t < 9; ++t) {
            #pragma unroll
            for (int cpass = 0; cpass < 2; ++cpass) {
                const int flip = cpass << 6;
                f16x8 bf;
                if ((okm >> t) & 1) {
                    const f16x8 p00 = *(const f16x8*)(winp + (o00[t] ^ flip));
                    const f16x8 p01 = *(const f16x8*)(winp + (o01[t] ^ flip));
                    const f16x8 p10 = *(const f16x8*)(winp + (o10[t] ^ flip));
                    const f16x8 p11 = *(const f16x8*)(winp + (o11[t] ^ flip));
                    bf = combine4(p00, p01, p10, p11,
                                  hA[t][0], hA[t][1], hB[t][0], hB[t][1]);
                } else {
                    const int ky = t / 3, kx = t - ky * 3;
                    const float dy = offs[(2 * t) * 128 + slot], dx = offs[(2 * t + 1) * 128 + slot];
                    const float py  = (float)(row - 1 + ky) + dy;
                    const float pxf = (float)(gpx - 1 + kx) + dx;
                    const int y0 = (int)floorf(py), x0 = (int)floorf(pxf);
                    const int cy0 = min(max(y0, 0), HH - 1), cy1 = min(max(y0 + 1, 0), HH - 1);
                    const int cx0 = min(max(x0, 0), WW - 1), cx1 = min(max(x0 + 1, 0), WW - 1);
                    const int ch8 = cpass * 4 + cg;
                    const f16x8 p00 = *(const f16x8*)(xt + xt_idx(b, cy0, cx0) + ch8 * 8);
                    const f16x8 p01 = *(const f16x8*)(xt + xt_idx(b, cy0, cx1) + ch8 * 8);
                    const f16x8 p10 = *(const f16x8*)(xt + xt_idx(b, cy1, cx0) + ch8 * 8);
                    const f16x8 p11 = *(const f16x8*)(xt + xt_idx(b, cy1, cx1) + ch8 * 8);
                    bf = combine4(p00, p01, p10, p11,
                                  hA[t][0], hA[t][1], hB[t][0], hB[t][1]);
                }
                const char* wa = wdef_l + (((t * 2 + cpass) * 4) * 64 + l) * 16;
                acc0 = __builtin_amdgcn_mfma_f32_16x16x32_f16(*(const f16x8*)(wa + 0 * 1024), bf, acc0, 0, 0, 0);
                acc1 = __builtin_amdgcn_mfma_f32_16x16x32_f16(*(const f16x8*)(wa + 1 * 1024), bf, acc1, 0, 0, 0);
                acc2 = __builtin_amdgcn_mfma_f32_16x16x32_f16(*(const f16x8*)(wa + 2 * 1024), bf, acc2, 0, 0, 0);
                acc3 = __builtin_amdgcn_mfma_f32_16x16x32_f16(*(const f16x8*)(wa + 3 * 1024), bf, acc3, 0, 0, 0);
            }
        }
    }

    // ---- epilogue ----
    #pragma unroll
    for (int mt = 0; mt < 4; ++mt) {
        const f32x4 a = (mt == 0) ? acc0 : (mt == 1) ? acc1 : (mt == 2) ? acc2 : acc3;
        #pragma unroll
        for (int reg = 0; reg < 4; ++reg) {
            const int o = mt * 16 + cg * 4 + reg;
            out[(((size_t)b * OO + o) * HH + row) * WW + gpx] = a[reg] + dbias[o];
        }
    }
}

extern "C" void kernel_launch(void* const* d_in, const int* in_sizes, int n_in,
                              void* d_out, int out_size, void* d_ws, size_t ws_size,
                              hipStream_t stream) {
    const float* x     = (const float*)d_in[0];
    const float* offw  = (const float*)d_in[1];
    const float* offb  = (const float*)d_in[2];
    const float* dw    = (const float*)d_in[3];
    const float* dbias = (const float*)d_in[4];
    float* out = (float*)d_out;

    const size_t XT_BYTES    = (size_t)BB * HH * WW * CC * sizeof(f16);   // 8 MiB
    const size_t WAOFF_BYTES = 36 * 64 * 8 * sizeof(f16);

    f16* xt     = (f16*)d_ws;
    f16* wa_off = (f16*)((char*)d_ws + XT_BYTES);
    f16* wa_def = (f16*)((char*)d_ws + XT_BYTES + WAOFF_BYTES);
    (void)ws_size; (void)in_sizes; (void)n_in; (void)out_size;

    const int LDS_BYTES = 162432;
    (void)hipFuncSetAttribute((const void*)deform_mfma,
                              hipFuncAttributeMaxDynamicSharedMemorySize, LDS_BYTES);

    prep_all<<<512 + 27, 256, 0, stream>>>(x, offw, dw, xt, wa_off, wa_def);
    deform_mfma<<<512, 512, LDS_BYTES, stream>>>(xt, wa_off, offb, wa_def, dbias, out);
}